// Round 10
// baseline (367.508 us; speedup 1.0000x reference)
//
#include <hip/hip_runtime.h>
#include <hip/hip_bf16.h>
#include <stdint.h>
#include <string.h>

using u16 = unsigned short;
typedef __attribute__((ext_vector_type(8))) short short8;
typedef __attribute__((ext_vector_type(4))) short short4v;
typedef __attribute__((ext_vector_type(4))) float f32x4;

__device__ __forceinline__ u16 f2bf(float f) {
  union { float f; unsigned int u; } x; x.f = f;
  unsigned int u = x.u;
  return (u16)((u + 0x7fffu + ((u >> 16) & 1u)) >> 16);
}
__device__ __forceinline__ unsigned int pk_bf16(float a, float b) {
  float2 t; t.x = a; t.y = b;
  __hip_bfloat162 h = __float22bfloat162_rn(t);
  unsigned int u; memcpy(&u, &h, 4);
  return u;
}
__device__ __forceinline__ void gl_lds16(const u16* g, u16* l) {
  __builtin_amdgcn_global_load_lds((const __attribute__((address_space(1))) void*)g,
                                   (__attribute__((address_space(3))) void*)l, 16, 0, 0);
}

// ---------------- x ingestion: fp32 -> internal bf16 ----------------
__global__ void __launch_bounds__(256) conv_x(
    const float* __restrict__ in, u16* __restrict__ out, int n4) {
  const int t = blockIdx.x * 256 + threadIdx.x;
  if (t >= n4) return;
  const float4 v = ((const float4*)in)[t];
  uint2 o;
  o.x = pk_bf16(v.x, v.y);
  o.y = pk_bf16(v.z, v.w);
  ((uint2*)out)[t] = o;
}

// ---- 64x64-tile weight transpose, fp32 in -> bf16 out, all 4 weights via z ----
__global__ void __launch_bounds__(256) transpose_w(
    const float* __restrict__ W0, const float* __restrict__ W1,
    const float* __restrict__ W2, const float* __restrict__ W3,
    u16* __restrict__ Wt) {
  __shared__ alignas(16) u16 t[64][65];
  const int z = blockIdx.z;
  const float* in = (z == 0) ? W0 : (z == 1) ? W1 : (z == 2) ? W2 : W3;
  u16* out = Wt + (size_t)z * 1024 * 1024;
  const int tx = threadIdx.x & 63, ty = threadIdx.x >> 6;
  const int r0 = blockIdx.y * 64, c0 = blockIdx.x * 64;
#pragma unroll
  for (int rr = ty; rr < 64; rr += 4) t[rr][tx] = f2bf(in[(size_t)(r0 + rr) * 1024 + c0 + tx]);
  __syncthreads();
#pragma unroll
  for (int rr = ty; rr < 64; rr += 4) out[(size_t)(c0 + rr) * 1024 + r0 + tx] = t[tx][rr];
}

// ---------------- shared GEMM core: 128x128 tile, BK=32, m97-style ----------------
__device__ __forceinline__ void gemm_core(
    const u16* __restrict__ A, const u16* __restrict__ Bt,
    u16* As, u16* Bs, int m0, int n0, int K, f32x4 (&acc)[4][4]) {
  const int tid = threadIdx.x;
  const int wave = tid >> 6, lane = tid & 63;
  const int quad = lane >> 4, l16 = lane & 15;
  const int wr = wave >> 1, wc = wave & 1;
  const int lr = lane >> 2, lc = (lane & 3) * 8;
  for (int k0 = 0; k0 < K; k0 += 32) {
    __syncthreads();
#pragma unroll
    for (int t = 0; t < 2; ++t) {
      const int c = wave + t * 4;
      gl_lds16(A  + (size_t)(m0 + c * 16 + lr) * K + k0 + lc, &As[c * 16 * 32]);
      gl_lds16(Bt + (size_t)(n0 + c * 16 + lr) * K + k0 + lc, &Bs[c * 16 * 32]);
    }
    __syncthreads();
    short8 af[4], bfr[4];
#pragma unroll
    for (int i = 0; i < 4; ++i)
      af[i] = *(const short8*)&As[(wr * 64 + i * 16 + l16) * 32 + quad * 8];
#pragma unroll
    for (int j = 0; j < 4; ++j)
      bfr[j] = *(const short8*)&Bs[(wc * 64 + j * 16 + l16) * 32 + quad * 8];
#pragma unroll
    for (int i = 0; i < 4; ++i)
#pragma unroll
      for (int j = 0; j < 4; ++j)
        acc[i][j] = __builtin_amdgcn_mfma_f32_16x16x32_bf16(af[i], bfr[j], acc[i][j], 0, 0, 0);
  }
}

// ---------------- fused QKV GEMM ----------------
__global__ void __launch_bounds__(256) gemm_qkv(
    const u16* __restrict__ A, const u16* __restrict__ Wt,
    const float* __restrict__ bq, const float* __restrict__ bk, const float* __restrict__ bv,
    u16* __restrict__ Qb, u16* __restrict__ Kb, u16* __restrict__ Vtb) {
  __shared__ alignas(16) u16 As[128 * 32];
  __shared__ alignas(16) u16 Bs[128 * 32];
  const int tsel = blockIdx.x >> 3;
  const int n0 = (blockIdx.x & 7) * 128;
  const int m0 = blockIdx.y * 128;
  const u16* Bt = Wt + (size_t)tsel * 1048576;
  const float* bias = (tsel == 0) ? bq : (tsel == 1) ? bk : bv;

  f32x4 acc[4][4];
#pragma unroll
  for (int i = 0; i < 4; ++i)
#pragma unroll
    for (int j = 0; j < 4; ++j) acc[i][j] = (f32x4){0.f, 0.f, 0.f, 0.f};

  gemm_core(A, Bt, As, Bs, m0, n0, 1024, acc);

  const int tid = threadIdx.x;
  const int wave = tid >> 6, lane = tid & 63;
  const int quad = lane >> 4, l16 = lane & 15;
  const int wr = wave >> 1, wc = wave & 1;

  if (tsel < 2) {
    u16* C = tsel ? Kb : Qb;
#pragma unroll
    for (int j = 0; j < 4; ++j) {
      const int n = n0 + wc * 64 + j * 16 + l16;
      const float bvf = bias[n];
      const int h = n >> 6, d = n & 63;
#pragma unroll
      for (int i = 0; i < 4; ++i) {
        const int mbase = m0 + wr * 64 + i * 16 + quad * 4;
#pragma unroll
        for (int r = 0; r < 4; ++r) {
          const int m = mbase + r;
          const int b = m >> 11, s = m & 2047;
          C[((((size_t)b * 16 + h) * 2048) + s) * 64 + d] = f2bf(acc[i][j][r] + bvf);
        }
      }
    }
  } else {
#pragma unroll
    for (int j = 0; j < 4; ++j) {
      const int n = n0 + wc * 64 + j * 16 + l16;
      const float bvf = bias[n];
      const int h = n >> 6, d = n & 63;
#pragma unroll
      for (int i = 0; i < 4; ++i) {
        const int mbase = m0 + wr * 64 + i * 16 + quad * 4;  // s, multiple of 4
        const int b = mbase >> 11, s = mbase & 2047;
        uint2 o;
        o.x = pk_bf16(acc[i][j][0] + bvf, acc[i][j][1] + bvf);
        o.y = pk_bf16(acc[i][j][2] + bvf, acc[i][j][3] + bvf);
        *(uint2*)&Vtb[(((size_t)b * 16 + h) * 64 + d) * 2048 + s] = o;
      }
    }
  }
}

// ---------------- output-projection GEMM: fp32 out ----------------
__global__ void __launch_bounds__(256) gemm_out(
    const u16* __restrict__ A, const u16* __restrict__ Bt,
    const float* __restrict__ bias, float* __restrict__ C, int N) {
  __shared__ alignas(16) u16 As[128 * 32];
  __shared__ alignas(16) u16 Bs[128 * 32];
  const int m0 = blockIdx.y * 128;
  const int n0 = blockIdx.x * 128;
  f32x4 acc[4][4];
#pragma unroll
  for (int i = 0; i < 4; ++i)
#pragma unroll
    for (int j = 0; j < 4; ++j) acc[i][j] = (f32x4){0.f, 0.f, 0.f, 0.f};

  gemm_core(A, Bt, As, Bs, m0, n0, 1024, acc);

  const int tid = threadIdx.x;
  const int wave = tid >> 6, lane = tid & 63;
  const int quad = lane >> 4, l16 = lane & 15;
  const int wr = wave >> 1, wc = wave & 1;
#pragma unroll
  for (int j = 0; j < 4; ++j) {
    const int n = n0 + wc * 64 + j * 16 + l16;
    const float bvf = bias[n];
#pragma unroll
    for (int i = 0; i < 4; ++i) {
      const int mbase = m0 + wr * 64 + i * 16 + quad * 4;
#pragma unroll
      for (int r = 0; r < 4; ++r)
        C[(size_t)(mbase + r) * N + n] = acc[i][j][r] + bvf;
    }
  }
}

// ---------------- Flash attention: register-P PV via 16x16x16 bf16 MFMA ----------------
// Layout validated by R9 (error was hazard-level, not layout-level). PV now uses the
// builtin (compiler manages XDL wait-states); asm fallback carries explicit s_nops.
__global__ void __launch_bounds__(256) flash_attn(
    const u16* __restrict__ Q, const u16* __restrict__ Kp,
    const u16* __restrict__ Vt, u16* __restrict__ Aout) {
  __shared__ alignas(16) u16 Ks[64 * 64];
  __shared__ alignas(16) u16 Vs[64 * 64];   // [d][s] tile, 16B-chunk XOR swizzled

  const int tid = threadIdx.x;
  const int wave = tid >> 6;
  const int lane = tid & 63;
  const int quad = lane >> 4;
  const int l16 = lane & 15;
  const int bh = blockIdx.y;
  const int q0 = blockIdx.x * 64;
  const int b = bh >> 4, h = bh & 15;

  const u16* Qg = Q + (size_t)bh * 2048 * 64;
  const u16* Kg = Kp + (size_t)bh * 2048 * 64;
  const u16* Vg = Vt + (size_t)bh * 64 * 2048;

  const int lr8 = lane >> 3;                 // staging row within 8-row chunk
  const int cbg = ((lane & 7) ^ lr8) * 8;    // swizzled global chunk offset
  const int sw = (l16 & 7) * 8;              // b128 fragment-read swizzle
  const int swq = l16 & 7;                   // chunk-granular swizzle for b64 reads

  // ---- stage Q tile through Ks once; hoist Q B-fragments into registers ----
#pragma unroll
  for (int t = 0; t < 2; ++t) {
    const int c = wave * 2 + t;
    gl_lds16(Qg + (size_t)(q0 + c * 8 + lr8) * 64 + cbg, &Ks[c * 8 * 64]);
  }
  __syncthreads();
  short8 qf[2];
#pragma unroll
  for (int ks = 0; ks < 2; ++ks)
    qf[ks] = *(const short8*)&Ks[(wave * 16 + l16) * 64 + (((ks * 4 + quad) * 8) ^ sw)];

  f32x4 oacc[4];  // oacc[t2][r] = O^T[d=t2*16+quad*4+r][q=l16]
#pragma unroll
  for (int t = 0; t < 4; ++t) oacc[t] = (f32x4){0.f, 0.f, 0.f, 0.f};
  float l = 0.f;  // per-lane partial (own quad's kv only); cross-quad reduce at end
  const float cexp = 0.125f * 1.44269504088896340736f;  // scale * log2(e)

  for (int kt = 0; kt < 32; ++kt) {
    const int s0 = kt * 64;
    __syncthreads();   // all qf reads done (iter 0) / Ks reuse safe
#pragma unroll
    for (int t = 0; t < 2; ++t) {
      const int c = wave * 2 + t;
      gl_lds16(Kg + (size_t)(s0 + c * 8 + lr8) * 64 + cbg, &Ks[c * 8 * 64]);
      gl_lds16(Vg + (size_t)(c * 8 + lr8) * 2048 + s0 + cbg, &Vs[c * 8 * 64]);
    }
    __syncthreads();

    // S^T = K-tile @ Q^T  (16x16x32, A=K from LDS, B=Q from registers)
    f32x4 sacc[4];
#pragma unroll
    for (int t = 0; t < 4; ++t) sacc[t] = (f32x4){0.f, 0.f, 0.f, 0.f};
#pragma unroll
    for (int ks = 0; ks < 2; ++ks) {
#pragma unroll
      for (int t = 0; t < 4; ++t) {
        const short8 akf = *(const short8*)&Ks[(t * 16 + l16) * 64 + (((ks * 4 + quad) * 8) ^ sw)];
        sacc[t] = __builtin_amdgcn_mfma_f32_16x16x32_bf16(akf, qf[ks], sacc[t], 0, 0, 0);
      }
    }

    // max-free softmax; pack P into 16x16x16 B-fragments (registers)
    short4v pk[4];
#pragma unroll
    for (int t = 0; t < 4; ++t) {
      const float p0 = exp2f(sacc[t][0] * cexp);
      const float p1 = exp2f(sacc[t][1] * cexp);
      const float p2 = exp2f(sacc[t][2] * cexp);
      const float p3 = exp2f(sacc[t][3] * cexp);
      l += (p0 + p1) + (p2 + p3);
      uint2 u;
      u.x = pk_bf16(p0, p1);
      u.y = pk_bf16(p2, p3);
      memcpy(&pk[t], &u, 8);
    }

    // O^T += V @ P^T via 16 x mfma 16x16x16 (A=V b64 from LDS, B=pk registers)
#pragma unroll
    for (int t = 0; t < 4; ++t) {
#pragma unroll
      for (int t2 = 0; t2 < 4; ++t2) {
        const short4v vf = *(const short4v*)&Vs[(t2 * 16 + l16) * 64 +
                                               (((2 * t + (quad >> 1)) ^ swq) * 8) + (quad & 1) * 4];
#if __has_builtin(__builtin_amdgcn_mfma_f32_16x16x16bf16_1k)
        oacc[t2] = __builtin_amdgcn_mfma_f32_16x16x16bf16_1k(vf, pk[t], oacc[t2], 0, 0, 0);
#else
        // fallback: explicit XDL hazard guards inside the asm block
        asm volatile("s_nop 2\n\tv_mfma_f32_16x16x16_bf16 %0, %1, %2, %0"
                     : "+v"(oacc[t2]) : "v"(vf), "v"(pk[t]));
#endif
      }
    }
#if !__has_builtin(__builtin_amdgcn_mfma_f32_16x16x16bf16_1k)
    // WAR guard: in-flight MFMAs must finish reading pk before next iter's packs rewrite it
    asm volatile("s_nop 7" ::);
#endif
  }

#if !__has_builtin(__builtin_amdgcn_mfma_f32_16x16x16bf16_1k)
  // MFMA -> VALU-read hazard guard for the asm accumulators
  asm volatile("s_nop 7\n\ts_nop 7\n\ts_nop 3" ::);
#endif

  l += __shfl_xor(l, 16);
  l += __shfl_xor(l, 32);
  const float inv = 1.0f / l;
  const int qrow = q0 + wave * 16 + l16;
  const size_t base = ((size_t)b * 2048 + qrow) * 1024 + h * 64 + quad * 4;
#pragma unroll
  for (int t = 0; t < 4; ++t) {
    uint2 o;
    o.x = pk_bf16(oacc[t][0] * inv, oacc[t][1] * inv);
    o.y = pk_bf16(oacc[t][2] * inv, oacc[t][3] * inv);
    *(uint2*)&Aout[base + t * 16] = o;
  }
}

extern "C" void kernel_launch(void* const* d_in, const int* in_sizes, int n_in,
                              void* d_out, int out_size, void* d_ws, size_t ws_size,
                              hipStream_t stream) {
  (void)in_sizes; (void)n_in; (void)out_size; (void)ws_size;
  const float* x  = (const float*)d_in[0];
  const float* Wq = (const float*)d_in[1];
  const float* bq = (const float*)d_in[2];
  const float* Wk = (const float*)d_in[3];
  const float* bk = (const float*)d_in[4];
  const float* Wv = (const float*)d_in[5];
  const float* bv = (const float*)d_in[6];
  const float* Wo = (const float*)d_in[7];
  const float* bo = (const float*)d_in[8];
  float* out = (float*)d_out;

  u16* ws = (u16*)d_ws;
  const size_t SZ = (size_t)4 * 16 * 2048 * 64;  // 16 MiB regions
  u16* xb   = ws;               // A (reused for Attn after gemm_qkv)
  u16* Qb   = ws + SZ;          // B
  u16* Kb   = ws + 2 * SZ;      // C
  u16* Vtb  = ws + 3 * SZ;      // D (V written directly transposed)
  u16* Wt   = ws + 4 * SZ;      // E (4 transposed weights)
  u16* Attn = ws;               // A alias

  dim3 blk(256);
  conv_x<<<dim3(8192), blk, 0, stream>>>(x, xb, 2097152);
  transpose_w<<<dim3(16, 16, 4), blk, 0, stream>>>(Wq, Wk, Wv, Wo, Wt);
  gemm_qkv<<<dim3(24, 64), blk, 0, stream>>>(xb, Wt, bq, bk, bv, Qb, Kb, Vtb);
  flash_attn<<<dim3(32, 64), blk, 0, stream>>>(Qb, Kb, Vtb, Attn);
  gemm_out<<<dim3(8, 64), blk, 0, stream>>>(Attn, Wt + (size_t)3 * 1048576, bo, out, 1024);
}